// Round 5
// baseline (72.656 us; speedup 1.0000x reference)
//
#include <hip/hip_runtime.h>

// Problem constants (static per reference)
constexpr int B_DIM   = 32;
constexpr int M_EDGES = 4096;     // edges per batch (2^12)
constexpr int F_DIM   = 64;
constexpr int N_ATOMS = 128;
constexpr int QMAX    = 192;      // queue cap; row count ~ Binomial(4096, 1/128), mean 32

using f32x4 = __attribute__((ext_vector_type(4))) float;

// One workgroup per output row (b, i). The row tile [128][64] f32 lives in
// LDS (32 KB); edges matching this row are found by scanning the batch's
// pair list (L2-resident) and accumulated via ds_add_f32 (conflict-free:
// row stride 64 floats -> 2-way bank alias = free). The final contiguous
// 32 KB store doubles as the zero-fill. No workspace, no memset, 1 dispatch.
__global__ __launch_bounds__(256) void fused_row_kernel(
    const float* __restrict__ edge,   // [B, M, F]
    const int*   __restrict__ pair,   // [B, M, 2] int32
    float*       __restrict__ out)    // [B, N, N, F]
{
    __shared__ float tile[N_ATOMS * F_DIM];   // 32 KB
    __shared__ unsigned int queue[QMAX];
    __shared__ int qcnt;

    // XCD-chunked swizzle: 4096 blocks, 8 XCDs -> 512 logical blocks per XCD.
    // Each batch's 128 row-blocks then live on one XCD: its 32 KB pair list
    // and 8 MB edge slab are fetched into that XCD's L2 once.
    const int bid     = (int)blockIdx.x;
    const int logical = (bid & 7) * 512 + (bid >> 3);
    const int b  = logical >> 7;      // batch
    const int i0 = logical & 127;     // output row i

    const int tid = threadIdx.x;

    if (tid == 0) qcnt = 0;
    f32x4* t4 = (f32x4*)tile;
    #pragma unroll
    for (int k = 0; k < 8; ++k)       // 2048 float4 / 256 threads
        t4[tid + 256 * k] = (f32x4)0.0f;
    __syncthreads();

    // Phase 2: scan this batch's pairs (coalesced, strided). ~32 matches.
    const int2* bp = (const int2*)pair + (size_t)b * M_EDGES;
    #pragma unroll
    for (int k = 0; k < 16; ++k) {
        const int t = tid + 256 * k;
        const int2 ij = bp[t];
        if (ij.x == i0) {
            const int pos = atomicAdd(&qcnt, 1);
            if (pos < QMAX) queue[pos] = (unsigned int)((ij.y << 12) | t);
        }
    }
    __syncthreads();

    // Phase 3: one wave per queue entry; lane = feature. 256 B coalesced
    // edge read + LDS float atomic add (waves may share a j).
    int qc = qcnt; if (qc > QMAX) qc = QMAX;
    const int wv = tid >> 6, lane = tid & 63;
    const float* eb = edge + (size_t)b * M_EDGES * F_DIM;
    for (int t = wv; t < qc; t += 4) {
        const unsigned int ent = queue[t];        // broadcast within wave
        const int m = (int)(ent & 4095u);
        const int j = (int)(ent >> 12);
        const float v = eb[(size_t)m * F_DIM + lane];
        atomicAdd(&tile[(j << 6) + lane], v);
    }
    __syncthreads();

    // Phase 4: contiguous 32 KB row store (this IS the zero-fill).
    f32x4* o4 = (f32x4*)(out + ((size_t)b * N_ATOMS + i0) * (N_ATOMS * F_DIM));
    #pragma unroll
    for (int k = 0; k < 8; ++k)
        o4[tid + 256 * k] = t4[tid + 256 * k];
}

extern "C" void kernel_launch(void* const* d_in, const int* in_sizes, int n_in,
                              void* d_out, int out_size, void* d_ws, size_t ws_size,
                              hipStream_t stream) {
    const float* edge = (const float*)d_in[0];
    const int*   pair = (const int*)d_in[1];
    float*       out  = (float*)d_out;

    // 32 batches x 128 rows = 4096 workgroups, 256 threads each.
    fused_row_kernel<<<B_DIM * N_ATOMS, 256, 0, stream>>>(edge, pair, out);
}

// Round 6
// 68.214 us; speedup vs baseline: 1.0651x; 1.0651x over previous
//
#include <hip/hip_runtime.h>

// Problem constants (static per reference)
constexpr int B_DIM   = 32;
constexpr int M_EDGES = 4096;     // edges per batch (2^12)
constexpr int F_DIM   = 64;
constexpr int N_ATOMS = 128;

constexpr int TOTAL_EDGES = B_DIM * M_EDGES;        // 131072
constexpr int BINS  = B_DIM * N_ATOMS * 2;          // (b, i, j-half) = 8192
constexpr int K_CAP = 64;                           // per-bin cap; Poisson(16), P(>=64) ~ 1e-12/bin

using f32x4 = __attribute__((ext_vector_type(4))) float;

// ---------------------------------------------------------------------------
// Kernel 1: bin edges by (batch, i, j>=64?). Entry packs local j (6b) and
// local edge id m (12b). One global atomicAdd + one 4B store per edge.
// ---------------------------------------------------------------------------
__global__ __launch_bounds__(256) void bin_edges_kernel(
    const int*    __restrict__ pair,      // [B, M, 2] int32
    int*          __restrict__ counts,    // [BINS]
    unsigned int* __restrict__ list)      // [BINS * K_CAP]
{
    const int e = blockIdx.x * 256 + threadIdx.x;   // grid == TOTAL_EDGES
    const int2 ij = ((const int2*)pair)[e];
    const int b = e >> 12;

    const int bin = (b << 8) | (ij.x << 1) | (ij.y >> 6);
    const int pos = atomicAdd(&counts[bin], 1);
    if (pos < K_CAP)
        list[bin * K_CAP + pos] =
            (unsigned int)(((ij.y & 63) << 12) | (e & (M_EDGES - 1)));
}

// ---------------------------------------------------------------------------
// Kernel 2: one block per half-row tile (64 j x 64 F = 16 KB LDS).
// Entries prefetched to LDS (no loop-carried L2 chain); one wave per edge:
// coalesced 256B edge read + ds_add_f32 (2-way bank alias = free).
// The contiguous 16 KB store IS the zero-fill; output written exactly once.
// 16 KB LDS + 256 thr -> 8 blocks/CU, 100% wave occupancy.
// ---------------------------------------------------------------------------
__global__ __launch_bounds__(256) void gather_halfrow_kernel(
    const float*        __restrict__ edge,    // [B, M, F]
    const int*          __restrict__ counts,  // [BINS]
    const unsigned int* __restrict__ list,    // [BINS * K_CAP]
    float*              __restrict__ out)     // [B, N, N, F]
{
    __shared__ float tile[64 * F_DIM];        // 16 KB
    __shared__ unsigned int q[K_CAP];

    const int bin = (int)blockIdx.x;
    const int tid = (int)threadIdx.x;

    int cnt = counts[bin];                    // uniform load (broadcast)
    if (cnt > K_CAP) cnt = K_CAP;

    // Prefetch all entries (one coalesced 256B burst; slots beyond cnt are
    // stale workspace but never read) while zeroing the tile.
    if (tid < K_CAP) q[tid] = list[bin * K_CAP + tid];
    f32x4* t4 = (f32x4*)tile;
    #pragma unroll
    for (int k = 0; k < 4; ++k)               // 1024 f32x4 / 256 threads
        t4[tid + 256 * k] = (f32x4)0.0f;
    __syncthreads();

    const int b    = bin >> 8;
    const int lane = tid & 63;
    const int wv   = tid >> 6;
    const float* eb = edge + (size_t)b * M_EDGES * F_DIM;

    // One edge per wave per iteration; mean cnt=16 -> ~4 iterations/wave.
    // Entry reads are LDS broadcasts; edge loads are independent across
    // iterations so they pipeline.
    for (int t = wv; t < cnt; t += 4) {
        const unsigned int ent = q[t];
        const int m  = (int)(ent & 4095u);
        const int jl = (int)((ent >> 12) & 63u);
        const float v = eb[m * F_DIM + lane];
        __hip_atomic_fetch_add(&tile[(jl << 6) + lane], v,
                               __ATOMIC_RELAXED, __HIP_MEMORY_SCOPE_WORKGROUP);
    }
    __syncthreads();

    // Contiguous 16 KB tile store: out offset = bin * 4096 floats
    // (bin = b<<8 | i<<1 | jh  ->  float offset b<<20 | i<<13 | jh<<12).
    f32x4* o4 = (f32x4*)(out + (size_t)bin * (64 * F_DIM));
    #pragma unroll
    for (int k = 0; k < 4; ++k)
        o4[tid + 256 * k] = t4[tid + 256 * k];
}

extern "C" void kernel_launch(void* const* d_in, const int* in_sizes, int n_in,
                              void* d_out, int out_size, void* d_ws, size_t ws_size,
                              hipStream_t stream) {
    const float* edge = (const float*)d_in[0];
    const int*   pair = (const int*)d_in[1];
    float*       out  = (float*)d_out;

    // Workspace: [0, 32 KiB) counts; [32 KiB, 32 KiB + 2 MiB) entry lists.
    int*          counts = (int*)d_ws;
    unsigned int* list   = (unsigned int*)((char*)d_ws + (size_t)BINS * sizeof(int));

    // Only the 32 KB counts need zeroing each call (list gated by counts).
    hipMemsetAsync(counts, 0, (size_t)BINS * sizeof(int), stream);

    bin_edges_kernel<<<TOTAL_EDGES / 256, 256, 0, stream>>>(pair, counts, list);

    gather_halfrow_kernel<<<BINS, 256, 0, stream>>>(edge, counts, list, out);
}

// Round 7
// 47.779 us; speedup vs baseline: 1.5206x; 1.4277x over previous
//
#include <hip/hip_runtime.h>

// Problem constants (static per reference)
constexpr int B_DIM   = 32;
constexpr int M_EDGES = 4096;     // edges per batch (2^12)
constexpr int F_DIM   = 64;
constexpr int N_ATOMS = 128;

constexpr int TOTAL_EDGES = B_DIM * M_EDGES;               // 131072
constexpr int CELLS       = B_DIM * N_ATOMS * N_ATOMS;     // 524288
constexpr int K_CAP       = 4;                             // dense 16B row per cell
constexpr unsigned int POOL_CAP = 4096;                    // overflow pool entries

using f32x4 = __attribute__((ext_vector_type(4))) float;
using u32x4 = __attribute__((ext_vector_type(4))) unsigned int;

// ---------------------------------------------------------------------------
// Kernel 1: bin edges by destination cell. One atomicAdd + one 4B store per
// edge (pool spill ~70 edges total; Poisson(0.25) per cell).
// ---------------------------------------------------------------------------
__global__ __launch_bounds__(256) void bin_edges_kernel(
    const int*          __restrict__ pair,      // [B, M, 2] int32
    int*                __restrict__ counts,    // [CELLS] (+ pool_cnt at CELLS)
    unsigned int*       __restrict__ list,      // [CELLS * 4]
    unsigned int*       __restrict__ pool_cnt,  // [1]
    unsigned long long* __restrict__ pool)      // [POOL_CAP]
{
    const int e = blockIdx.x * 256 + threadIdx.x;   // grid == TOTAL_EDGES
    const int2 ij = ((const int2*)pair)[e];
    const int b = e >> 12;

    const int cell = (b << 14) | (ij.x << 7) | ij.y;
    const int pos = atomicAdd(&counts[cell], 1);
    if (pos < K_CAP) {
        list[cell * K_CAP + pos] = (unsigned int)e;
    } else {
        const unsigned int pi = atomicAdd(pool_cnt, 1u);
        if (pi < POOL_CAP)
            pool[pi] = ((unsigned long long)(unsigned int)cell << 32) | (unsigned int)e;
    }
}

// ---------------------------------------------------------------------------
// Kernel 2: 16 threads per cell, one float4 of F each. Metadata = one dense
// 16B uint4 row (fully used -> no line overfetch). Unused ids clamp to id0
// (aliases the already-fetched edge line); blend via 0/1 scale. No barriers,
// no LDS: maximal store concurrency (the R2 property that won). Output
// written exactly once -> the write IS the zero-fill.
// ---------------------------------------------------------------------------
__global__ __launch_bounds__(256) void gather_write_kernel(
    const float*              __restrict__ edge,      // [B, M, F]
    const int*                __restrict__ counts,    // [CELLS]
    const unsigned int*       __restrict__ list,      // [CELLS * 4]
    const unsigned int*       __restrict__ pool_cnt,  // [1]
    const unsigned long long* __restrict__ pool,      // [POOL_CAP]
    float*                    __restrict__ out)       // [B, N, N, F]
{
    const int tid  = blockIdx.x * 256 + threadIdx.x;
    const int cell = tid >> 4;          // 16 threads per cell
    const int q    = tid & 15;          // which float4 of the 64 features

    const int cnt = counts[cell];       // broadcast across the 16 lanes

    f32x4 acc = (f32x4)0.0f;
    const f32x4* ef = (const f32x4*)edge;

    if (cnt > 0) {
        const u32x4 r = *reinterpret_cast<const u32x4*>(list + (size_t)cell * K_CAP);
        const unsigned int e0 = r.x;                  // valid: cnt >= 1
        const unsigned int e1 = cnt > 1 ? r.y : e0;   // clamp: stale slots never used
        const unsigned int e2 = cnt > 2 ? r.z : e0;
        const unsigned int e3 = cnt > 3 ? r.w : e0;

        const f32x4 a0 = ef[(size_t)e0 * 16 + q];     // 4 independent loads
        const f32x4 a1 = ef[(size_t)e1 * 16 + q];
        const f32x4 a2 = ef[(size_t)e2 * 16 + q];
        const f32x4 a3 = ef[(size_t)e3 * 16 + q];

        acc = a0;
        acc += a1 * (cnt > 1 ? 1.0f : 0.0f);
        acc += a2 * (cnt > 2 ? 1.0f : 0.0f);
        acc += a3 * (cnt > 3 ? 1.0f : 0.0f);

        if (cnt > K_CAP) {              // ~67 cells in the whole problem
            unsigned int pc = *pool_cnt;
            pc = pc > POOL_CAP ? POOL_CAP : pc;
            for (unsigned int t = 0; t < pc; ++t) {   // pool is L2-hot, ~70 entries
                const unsigned long long ent = pool[t];
                if ((int)(ent >> 32) == cell)
                    acc += ef[(size_t)(unsigned int)ent * 16 + q];
            }
        }
    }

    ((f32x4*)out)[(size_t)cell * 16 + q] = acc;       // cacheable store (L3-absorbable)
}

extern "C" void kernel_launch(void* const* d_in, const int* in_sizes, int n_in,
                              void* d_out, int out_size, void* d_ws, size_t ws_size,
                              hipStream_t stream) {
    const float* edge = (const float*)d_in[0];
    const int*   pair = (const int*)d_in[1];
    float*       out  = (float*)d_out;

    // Workspace layout:
    //   [0, 2 MiB)                 counts (int32 x CELLS)
    //   [2 MiB, 2 MiB + 4)         pool counter
    //   [2 MiB + 16, + 32 KiB)     overflow pool (u64 x POOL_CAP)
    //   [2 MiB + 64 KiB, + 8 MiB)  dense list (uint4 per cell)
    char* ws = (char*)d_ws;
    int*                counts   = (int*)ws;
    unsigned int*       pool_cnt = (unsigned int*)(ws + (size_t)CELLS * 4);
    unsigned long long* pool     = (unsigned long long*)(ws + (size_t)CELLS * 4 + 16);
    unsigned int*       list     = (unsigned int*)(ws + (size_t)CELLS * 4 + 65536);

    // Zero counts + pool counter in one memset (pool/list gated by counts).
    hipMemsetAsync(ws, 0, (size_t)CELLS * 4 + 16, stream);

    bin_edges_kernel<<<TOTAL_EDGES / 256, 256, 0, stream>>>(pair, counts, list, pool_cnt, pool);

    gather_write_kernel<<<(CELLS * 16) / 256, 256, 0, stream>>>(edge, counts, list, pool_cnt, pool, out);
}